// Round 6
// baseline (244.644 us; speedup 1.0000x reference)
//
#include <hip/hip_runtime.h>

// Problem constants: VOCAB=100000, EMB=300, B=2048, L=200, H=128, OUT=20
#define BB   2048
#define LL   200
#define EMB  300
#define HH   128
#define OUTD 20
#define NSRT 256        // bitonic sort width (LL padded with INT_MAX)
#define RPW  (LL / 4)   // 50 rows per wave
#define DP   6          // main-loop pipeline depth (rows in flight per wave)

// One block per sample, 256 threads = 4 waves.
// Phase 0: bitonic sort of the 200 indices (L3 locality across co-resident blocks).
// Phase 1a (channels 0..255): branch-free gather, lane j = float4 j of the row.
//   Explicit D=6 rotating register buffer, fully unrolled, SGPR row bases via
//   readlane -> 6 rows (7.2 KB) guaranteed in flight per wave. No branch in the
//   loop body (R5's per-iteration `if (hasb)` fenced the scheduler to depth ~1).
// Phase 1b (channels 256..299): packed tail — 5 rows x 11 float4 per iteration,
//   lanes 55..63 clamped to duplicate lanes 44..52 (identical values, collision-
//   safe LDS writes), D=2 pipeline.
// Phase 2: LDS reductions, split-k W1 GEMV, tiny W2 GEMV.
__global__ __launch_bounds__(256) void fused_dnn(
    const int*   __restrict__ x,        // [B, L]
    const int*   __restrict__ lengths,  // [B]
    const float* __restrict__ table,    // [VOCAB, EMB]
    const float* __restrict__ W1,       // [EMB, H]
    const float* __restrict__ b1,       // [H]
    const float* __restrict__ W2,       // [H, OUT]
    const float* __restrict__ b2,       // [OUT]
    float*       __restrict__ out)      // [B, OUT]
{
    __shared__ int    idx_s[NSRT];
    __shared__ float4 part_s[4][64];    // main partials: [wave][float4 chan]
    __shared__ float4 tails[4][56];     // tail partials: [wave][sub*11+g]
    __shared__ float  rep_s[EMB];
    __shared__ float  h_part[2][HH];
    __shared__ float  h_s[HH];

    const int b    = blockIdx.x;
    const int t    = threadIdx.x;
    const int w    = t >> 6;            // wave 0..3
    const int lane = t & 63;

    idx_s[t] = (t < LL) ? x[b * LL + t] : 0x7FFFFFFF;
    __syncthreads();

    // ---- bitonic sort ascending (thread t owns slot t)
    #pragma unroll
    for (int k = 2; k <= NSRT; k <<= 1) {
        #pragma unroll
        for (int j = k >> 1; j > 0; j >>= 1) {
            const int ixj = t ^ j;
            if (ixj > t) {
                const int a0 = idx_s[t];
                const int a1 = idx_s[ixj];
                const bool up = ((t & k) == 0);
                if ((a0 > a1) == up) { idx_s[t] = a1; idx_s[ixj] = a0; }
            }
            __syncthreads();
        }
    }

    // lane j holds this wave's j-th row index (wave-interleaved sorted order)
    const int myidx = (lane < RPW) ? idx_s[w + 4 * lane] : 0;

    // ---- Phase 1a: channels 0..255, D=6 rotating pipeline, branch-free
    float4 acc_a = make_float4(0.f, 0.f, 0.f, 0.f);
    {
        float4 buf[DP];
        #pragma unroll
        for (int u = 0; u < DP; ++u) {
            const int r = __builtin_amdgcn_readlane(myidx, u);
            buf[u] = ((const float4*)(table + (size_t)r * EMB))[lane];
        }
        #pragma unroll
        for (int i = 0; i < RPW; ++i) {
            const float4 v = buf[i % DP];
            if (i + DP < RPW) {     // compile-time per unrolled instance
                const int r = __builtin_amdgcn_readlane(myidx, i + DP);
                buf[i % DP] = ((const float4*)(table + (size_t)r * EMB))[lane];
            }
            acc_a.x += v.x; acc_a.y += v.y; acc_a.z += v.z; acc_a.w += v.w;
        }
    }
    part_s[w][lane] = acc_a;

    // ---- Phase 1b: channels 256..299 (11 float4/row), 5 rows per iteration
    float4 acc_t = make_float4(0.f, 0.f, 0.f, 0.f);
    {
        const int g     = lane % 11;                  // float4 slot 64+g
        const int sub   = lane / 11;                  // 0..5
        const int sub_c = (lane < 55) ? sub : 4;      // lanes 55..63 dup 44..52
        float4 tbuf[2];
        #pragma unroll
        for (int u = 0; u < 2; ++u) {
            const int r = idx_s[w + 4 * (u * 5 + sub_c)];
            tbuf[u] = ((const float4*)(table + (size_t)r * EMB))[64 + g];
        }
        #pragma unroll
        for (int i = 0; i < RPW / 5; ++i) {           // 10 iterations
            const float4 v = tbuf[i & 1];
            if (i + 2 < RPW / 5) {
                const int r = idx_s[w + 4 * ((i + 2) * 5 + sub_c)];
                tbuf[i & 1] = ((const float4*)(table + (size_t)r * EMB))[64 + g];
            }
            acc_t.x += v.x; acc_t.y += v.y; acc_t.z += v.z; acc_t.w += v.w;
        }
        tails[w][sub_c * 11 + g] = acc_t;             // dup lanes write identical values
    }
    __syncthreads();

    // ---- cross-wave reduce + scale
    const float inv_len = 1.0f / (float)lengths[b];
    {
        const float* ps = (const float*)part_s;       // [4][256] floats
        float s = ps[t] + ps[256 + t] + ps[512 + t] + ps[768 + t];
        rep_s[t] = s * inv_len;                       // channels 0..255
    }
    if (t < (EMB - 256)) {                            // t<44: channels 256..299
        const int g4   = t >> 2;                      // 0..10
        const int comp = t & 3;
        const float* tf = (const float*)tails;        // [4][56][4] floats
        float s = 0.f;
        #pragma unroll
        for (int ww = 0; ww < 4; ++ww)
            #pragma unroll
            for (int sb = 0; sb < 5; ++sb)
                s += tf[(ww * 56 + sb * 11 + g4) * 4 + comp];
        rep_s[256 + t] = s * inv_len;
    }
    __syncthreads();

    // ---- h = relu(rep @ W1 + b1), split-k across the two half-blocks
    {
        const int half = t >> 7;
        const int col  = t & 127;
        float hacc = (half == 0) ? b1[col] : 0.0f;
        const int k0 = half * (EMB / 2);
        #pragma unroll 5
        for (int k = k0; k < k0 + EMB / 2; ++k)
            hacc = fmaf(rep_s[k], W1[k * HH + col], hacc);
        h_part[half][col] = hacc;
    }
    __syncthreads();
    if (t < HH)
        h_s[t] = fmaxf(h_part[0][t] + h_part[1][t], 0.0f);
    __syncthreads();

    // ---- logits = h @ W2 + b2
    if (t < OUTD) {
        float oacc = b2[t];
        #pragma unroll
        for (int k = 0; k < HH; ++k)
            oacc = fmaf(h_s[k], W2[k * OUTD + t], oacc);
        out[b * OUTD + t] = oacc;
    }
}

extern "C" void kernel_launch(void* const* d_in, const int* in_sizes, int n_in,
                              void* d_out, int out_size, void* d_ws, size_t ws_size,
                              hipStream_t stream) {
    const int*   x       = (const int*)  d_in[0];
    const int*   lengths = (const int*)  d_in[1];
    const float* table   = (const float*)d_in[2];
    const float* W1      = (const float*)d_in[3];
    const float* b1      = (const float*)d_in[4];
    const float* W2      = (const float*)d_in[5];
    const float* b2      = (const float*)d_in[6];
    float*       out     = (float*)d_out;

    fused_dnn<<<BB, 256, 0, stream>>>(x, lengths, table, W1, b1, W2, b2, out);
}